// Round 5
// baseline (776.144 us; speedup 1.0000x reference)
//
#include <hip/hip_runtime.h>
#include <hip/hip_bf16.h>
#include <math.h>

using bf16 = __hip_bfloat16;
using short8 = __attribute__((ext_vector_type(8))) short;
using floatx4 = __attribute__((ext_vector_type(4))) float;

constexpr int B = 64;
constexpr int N = 197;
constexpr int C = 768;
constexpr int NH = 12;
constexpr int HD = 64;
constexpr int HID = 3072;
constexpr int M = B * N;          // 12608 = 197 * 64
constexpr int MPAD = 12672;       // 99 * 128
constexpr float EPS = 1e-5f;

__device__ __forceinline__ float b2f(bf16 v) { return __bfloat162float(v); }
__device__ __forceinline__ bf16 f2b(float v) { return __float2bfloat16(v); }

// async global->LDS, 16B/lane. HW dest = wave-uniform base + lane*16.
typedef const __attribute__((address_space(1))) unsigned int* gas1_t;
typedef __attribute__((address_space(3))) unsigned int* las3_t;
__device__ __forceinline__ void load_lds16(const bf16* g, bf16* l) {
  __builtin_amdgcn_global_load_lds((gas1_t)g, (las3_t)l, 16, 0, 0);
}

// ---------------- f32 -> bf16 conversion (weights) -------------------------
__global__ void cvt_kernel(const float* __restrict__ src, bf16* __restrict__ dst, int n) {
  int i = blockIdx.x * 256 + threadIdx.x;
  if (i < n) dst[i] = f2b(src[i]);
}

// ---------------- block-wide sum over 256 threads (4 waves) ----------------
__device__ __forceinline__ float block_sum(float v, float* red) {
  #pragma unroll
  for (int off = 32; off >= 1; off >>= 1) v += __shfl_xor(v, off, 64);
  int w = threadIdx.x >> 6;
  if ((threadIdx.x & 63) == 0) red[w] = v;
  __syncthreads();
  float r = red[0] + red[1] + red[2] + red[3];
  __syncthreads();
  return r;
}

// ---------------- Kernel 1: LA pooling + channel MLP + fusion --------------
__global__ void la_pool_kernel(const float* __restrict__ x,
                               const float* __restrict__ f1w, const float* __restrict__ f1bias,
                               const float* __restrict__ f2w, const float* __restrict__ f2bias,
                               const float* __restrict__ vw,  const float* __restrict__ vbias,
                               float* __restrict__ fusion7) {
  int blk = blockIdx.x;
  int b = blk / 49, p = blk % 49;
  int h7 = p / 7, w7 = p % 7;
  int tid = threadIdx.x;
  int head = tid >> 4;     // 0..15
  int j = tid & 15;        // 0..15

  float sum = 0.f, mx = -3.0e38f;
  #pragma unroll
  for (int a = 0; a < 2; ++a) {
    #pragma unroll
    for (int bb = 0; bb < 2; ++bb) {
      int tok = 1 + (2 * h7 + a) * 14 + (2 * w7 + bb);
      const float* row = x + ((size_t)b * N + tok) * C + head * 48;
      #pragma unroll
      for (int s = 0; s < 3; ++s) {
        float v = row[j + 16 * s];
        sum += v;
        mx = fmaxf(mx, v);
      }
    }
  }
  #pragma unroll
  for (int off = 8; off >= 1; off >>= 1) {
    sum += __shfl_xor(sum, off, 64);
    mx = fmaxf(mx, __shfl_xor(mx, off, 64));
  }
  __shared__ float s_mean[16], s_max[16];
  if (j == 0) { s_mean[head] = sum / 192.f; s_max[head] = mx; }
  __syncthreads();
  if (tid < 16) {
    float hm = f1bias[0], hx = hm;
    #pragma unroll
    for (int h = 0; h < 16; ++h) {
      float w = f1w[h];
      hm += s_mean[h] * w;
      hx += s_max[h] * w;
    }
    hm = fmaxf(hm, 0.f);
    hx = fmaxf(hx, 0.f);
    float w2 = f2w[tid], b2v = f2bias[tid];
    float m   = hm * w2 + b2v;
    float mxv = hx * w2 + b2v;
    float fus = vw[0] * m + vw[1] * mxv + vbias[0];
    fusion7[((size_t)b * 16 + tid) * 49 + p] = fus;
  }
}

// ---------------- Kernel 2: gate (bilinear resize + sigmoid) + LN1 ---------
__global__ void gate_ln1_kernel(const float* __restrict__ x, const float* __restrict__ fusion7,
                                const float* __restrict__ g, const float* __restrict__ beta,
                                bf16* __restrict__ ln1) {
  int blk = blockIdx.x;
  int b = blk / N, n = blk % N;
  int tid = threadIdx.x;
  __shared__ float gates[16];
  __shared__ float red[4];

  if (tid < 16) {
    if (n > 0) {
      int hh = (n - 1) / 14, ww = (n - 1) % 14;
      float ch = fminf(fmaxf(hh * 0.5f - 0.25f, 0.f), 6.f);
      float cw = fminf(fmaxf(ww * 0.5f - 0.25f, 0.f), 6.f);
      int h0 = (int)floorf(ch); int h1 = min(h0 + 1, 6); float fh = ch - (float)h0;
      int w0 = (int)floorf(cw); int w1 = min(w0 + 1, 6); float fw = cw - (float)w0;
      const float* fp = fusion7 + ((size_t)b * 16 + tid) * 49;
      float v00 = fp[h0 * 7 + w0], v01 = fp[h0 * 7 + w1];
      float v10 = fp[h1 * 7 + w0], v11 = fp[h1 * 7 + w1];
      float v = (1.f - fh) * ((1.f - fw) * v00 + fw * v01)
              + fh        * ((1.f - fw) * v10 + fw * v11);
      gates[tid] = 1.f / (1.f + expf(-v));
    } else {
      gates[tid] = 0.f;   // cls token: multiplier (1+0) == identity
    }
  }
  __syncthreads();

  const float* xr = x + ((size_t)b * N + n) * C;
  float v[3];
  #pragma unroll
  for (int s = 0; s < 3; ++s) {
    int c = tid + 256 * s;
    v[s] = xr[c] * (1.f + gates[c / 48]);
  }
  float mu = block_sum(v[0] + v[1] + v[2], red) * (1.f / 768.f);
  float d0 = v[0] - mu, d1 = v[1] - mu, d2 = v[2] - mu;
  float var = block_sum(d0 * d0 + d1 * d1 + d2 * d2, red) * (1.f / 768.f);
  float rs = rsqrtf(var + EPS);
  bf16* orow = ln1 + ((size_t)b * N + n) * C;
  #pragma unroll
  for (int s = 0; s < 3; ++s) {
    int c = tid + 256 * s;
    orow[c] = f2b((v[s] - mu) * rs * g[c] + beta[c]);
  }
}

// ---------------- Kernel 3: LN over bf16 input -> bf16 ---------------------
__global__ void ln_bf16_kernel(const bf16* __restrict__ xin,
                               const float* __restrict__ g, const float* __restrict__ beta,
                               bf16* __restrict__ out) {
  int row = blockIdx.x;
  int tid = threadIdx.x;
  __shared__ float red[4];
  const bf16* xr = xin + (size_t)row * C;
  float v[3];
  #pragma unroll
  for (int s = 0; s < 3; ++s) v[s] = b2f(xr[tid + 256 * s]);
  float mu = block_sum(v[0] + v[1] + v[2], red) * (1.f / 768.f);
  float d0 = v[0] - mu, d1 = v[1] - mu, d2 = v[2] - mu;
  float var = block_sum(d0 * d0 + d1 * d1 + d2 * d2, red) * (1.f / 768.f);
  float rs = rsqrtf(var + EPS);
  bf16* orow = out + (size_t)row * C;
  #pragma unroll
  for (int s = 0; s < 3; ++s) {
    int c = tid + 256 * s;
    orow[c] = f2b((v[s] - mu) * rs * g[c] + beta[c]);
  }
}

// ---------------- Kernel 4: 128x128 tile, BK=64, XOR-swizzled LDS ----------
// C[M,Nc] = A[M,K]*W[Nc,K]^T + bias. EPI: 0=bias, 1=bias+exact gelu.
// LDS layout: sX[row][chunk] where chunk s holds global k-chunk (s ^ (row&7)).
// grid = (Nc/128, MPAD/128).
template <int EPI, int K>
__global__ __launch_bounds__(256, 3)
void gemm128(const bf16* __restrict__ A, const bf16* __restrict__ W,
             const float* __restrict__ bias,
             const float* __restrict__ resF, const bf16* __restrict__ resB,
             bf16* __restrict__ outB, float* __restrict__ outF, int Nc) {
  __shared__ __align__(16) bf16 sA[128 * 64];
  __shared__ __align__(16) bf16 sB[128 * 64];
  int tid = threadIdx.x;
  int wave = tid >> 6, lane = tid & 63, quad = lane >> 4, l16 = lane & 15;
  int m0 = blockIdx.y * 128;
  int n0 = blockIdx.x * 128;

  // staging: wave w covers rows w*32..w*32+31 (4 issues of 8 rows each).
  int ln8 = lane >> 3, seg = lane & 7;
  int sw = seg ^ ln8;                       // swizzled global chunk for this lane
  const bf16* gA = A + (size_t)(m0 + wave * 32 + ln8) * K + sw * 8;
  const bf16* gB = W + (size_t)(n0 + wave * 32 + ln8) * K + sw * 8;

  int wm = (wave & 1) * 64, wn = (wave >> 1) * 64;   // wave quadrant
  floatx4 acc[4][4] = {};

  for (int k0 = 0; k0 < K; k0 += 64) {
    #pragma unroll
    for (int i = 0; i < 4; ++i) {
      load_lds16(gA + (size_t)(i * 8) * K + k0, &sA[(wave * 32 + i * 8) * 64]);
      load_lds16(gB + (size_t)(i * 8) * K + k0, &sB[(wave * 32 + i * 8) * 64]);
    }
    __syncthreads();
    short8 af[4][2], bw[4][2];
    #pragma unroll
    for (int s = 0; s < 4; ++s) {
      int row = wm + s * 16 + l16;
      #pragma unroll
      for (int kh = 0; kh < 2; ++kh)
        af[s][kh] = *reinterpret_cast<const short8*>(
            &sA[row * 64 + (((quad + 4 * kh) ^ (row & 7)) * 8)]);
    }
    #pragma unroll
    for (int t = 0; t < 4; ++t) {
      int row = wn + t * 16 + l16;
      #pragma unroll
      for (int kh = 0; kh < 2; ++kh)
        bw[t][kh] = *reinterpret_cast<const short8*>(
            &sB[row * 64 + (((quad + 4 * kh) ^ (row & 7)) * 8)]);
    }
    #pragma unroll
    for (int kh = 0; kh < 2; ++kh)
      #pragma unroll
      for (int s = 0; s < 4; ++s)
        #pragma unroll
        for (int t = 0; t < 4; ++t)
          acc[s][t] = __builtin_amdgcn_mfma_f32_16x16x32_bf16(af[s][kh], bw[t][kh],
                                                              acc[s][t], 0, 0, 0);
    __syncthreads();
  }

  #pragma unroll
  for (int t = 0; t < 4; ++t) {
    int col = n0 + wn + t * 16 + l16;
    float bv = bias[col];
    #pragma unroll
    for (int s = 0; s < 4; ++s) {
      int rowb = m0 + wm + s * 16 + quad * 4;
      #pragma unroll
      for (int r = 0; r < 4; ++r) {
        int row = rowb + r;
        if (row < M) {
          float v = acc[s][t][r] + bv;
          if (EPI == 1) v = 0.5f * v * (1.f + erff(v * 0.7071067811865475f));
          size_t idx = (size_t)row * Nc + col;
          if (resF) v += resF[idx];
          if (resB) v += b2f(resB[idx]);
          if (outF) outF[idx] = v;
          if (outB) outB[idx] = f2b(v);
        }
      }
    }
  }
}

// ---------------- Kernel 5: MFMA attention, one block per (b, head) --------
__global__ void attn_mfma_kernel(const bf16* __restrict__ qkv, bf16* __restrict__ attn_o) {
  int bh = blockIdx.x;
  int h = bh % NH, b = bh / NH;
  int tid = threadIdx.x;
  int wave = tid >> 6, lane = tid & 63, quad = lane >> 4, l16 = lane & 15;

  __shared__ __align__(16) bf16 sVt[64][232];     // V^T: [d][m], m>=197 zero
  __shared__ __align__(16) bf16 sP[4][16][232];   // per-wave P: [q][m]

  const bf16* base = qkv + (size_t)b * N * 2304 + h * 64;

  {
    int d = tid & 63;
    for (int m = tid >> 6; m < 224; m += 4) {
      sVt[d][m] = (m < N) ? base[(size_t)m * 2304 + 1536 + d] : f2b(0.f);
    }
  }
  __syncthreads();

  const float scale = 0.125f;   // 64^-0.5

  for (int qt = wave; qt < 13; qt += 4) {
    int qr = min(qt * 16 + l16, N - 1);
    const bf16* qp = base + (size_t)qr * 2304;
    short8 aq0 = *reinterpret_cast<const short8*>(qp + quad * 8);
    short8 aq1 = *reinterpret_cast<const short8*>(qp + 32 + quad * 8);

    floatx4 s[13];
    #pragma unroll
    for (int kt = 0; kt < 13; ++kt) {
      int kr = min(kt * 16 + l16, N - 1);
      const bf16* kp = base + (size_t)kr * 2304 + 768;
      short8 bk0 = *reinterpret_cast<const short8*>(kp + quad * 8);
      short8 bk1 = *reinterpret_cast<const short8*>(kp + 32 + quad * 8);
      floatx4 acc = floatx4{0.f, 0.f, 0.f, 0.f};
      acc = __builtin_amdgcn_mfma_f32_16x16x32_bf16(aq0, bk0, acc, 0, 0, 0);
      acc = __builtin_amdgcn_mfma_f32_16x16x32_bf16(aq1, bk1, acc, 0, 0, 0);
      s[kt] = acc;
    }

    bool cv[13];
    #pragma unroll
    for (int kt = 0; kt < 13; ++kt) cv[kt] = (kt * 16 + l16) < N;

    float mx[4] = {-3.0e38f, -3.0e38f, -3.0e38f, -3.0e38f};
    #pragma unroll
    for (int kt = 0; kt < 13; ++kt) {
      #pragma unroll
      for (int r = 0; r < 4; ++r) {
        float sv = s[kt][r] * scale;
        s[kt][r] = sv;
        if (cv[kt]) mx[r] = fmaxf(mx[r], sv);
      }
    }
    #pragma unroll
    for (int off = 8; off >= 1; off >>= 1) {
      #pragma unroll
      for (int r = 0; r < 4; ++r) mx[r] = fmaxf(mx[r], __shfl_xor(mx[r], off, 64));
    }
    float sum[4] = {0.f, 0.f, 0.f, 0.f};
    #pragma unroll
    for (int kt = 0; kt < 13; ++kt) {
      #pragma unroll
      for (int r = 0; r < 4; ++r) {
        float e = cv[kt] ? expf(s[kt][r] - mx[r]) : 0.f;
        s[kt][r] = e;
        sum[r] += e;
      }
    }
    #pragma unroll
    for (int off = 8; off >= 1; off >>= 1) {
      #pragma unroll
      for (int r = 0; r < 4; ++r) sum[r] += __shfl_xor(sum[r], off, 64);
    }
    float inv[4];
    #pragma unroll
    for (int r = 0; r < 4; ++r) inv[r] = 1.f / sum[r];

    #pragma unroll
    for (int kt = 0; kt < 13; ++kt) {
      #pragma unroll
      for (int r = 0; r < 4; ++r)
        sP[wave][quad * 4 + r][kt * 16 + l16] = f2b(s[kt][r]);
    }
    #pragma unroll
    for (int r = 0; r < 4; ++r)
      sP[wave][quad * 4 + r][208 + l16] = f2b(0.f);

    floatx4 o[4] = {floatx4{0,0,0,0}, floatx4{0,0,0,0}, floatx4{0,0,0,0}, floatx4{0,0,0,0}};
    #pragma unroll
    for (int c = 0; c < 7; ++c) {
      short8 ap = *reinterpret_cast<const short8*>(&sP[wave][l16][c * 32 + quad * 8]);
      #pragma unroll
      for (int t = 0; t < 4; ++t) {
        short8 bv = *reinterpret_cast<const short8*>(&sVt[t * 16 + l16][c * 32 + quad * 8]);
        o[t] = __builtin_amdgcn_mfma_f32_16x16x32_bf16(ap, bv, o[t], 0, 0, 0);
      }
    }

    #pragma unroll
    for (int t = 0; t < 4; ++t) {
      #pragma unroll
      for (int r = 0; r < 4; ++r) {
        int qrow = qt * 16 + quad * 4 + r;
        if (qrow < N)
          attn_o[((size_t)b * N + qrow) * C + h * 64 + t * 16 + l16] = f2b(o[t][r] * inv[r]);
      }
    }
  }
}

// ---------------- host-side orchestration ----------------------------------
extern "C" void kernel_launch(void* const* d_in, const int* in_sizes, int n_in,
                              void* d_out, int out_size, void* d_ws, size_t ws_size,
                              hipStream_t stream) {
  (void)in_sizes; (void)n_in; (void)out_size; (void)ws_size;
  const float* x       = (const float*)d_in[0];
  const float* norm1_g = (const float*)d_in[1];
  const float* norm1_b = (const float*)d_in[2];
  const float* qkv_w   = (const float*)d_in[3];
  const float* qkv_b   = (const float*)d_in[4];
  const float* proj_w  = (const float*)d_in[5];
  const float* proj_b  = (const float*)d_in[6];
  const float* norm2_g = (const float*)d_in[7];
  const float* norm2_b = (const float*)d_in[8];
  const float* fc1_w   = (const float*)d_in[9];
  const float* fc1_b   = (const float*)d_in[10];
  const float* fc2_w   = (const float*)d_in[11];
  const float* fc2_b   = (const float*)d_in[12];
  const float* f1_w    = (const float*)d_in[13];
  const float* f1_b    = (const float*)d_in[14];
  const float* f2_w    = (const float*)d_in[15];
  const float* f2_b    = (const float*)d_in[16];
  const float* v_w     = (const float*)d_in[17];
  const float* v_b     = (const float*)d_in[18];
  float* out = (float*)d_out;

  char* ws = (char*)d_ws;
  // ws layout (~131.2 MB). Activation buffers padded to MPAD=12672 rows.
  float* fusion7 = (float*)(ws + 0);                //    200,704
  bf16*  qkv_wb  = (bf16*)(ws + 262144);            //  3,538,944
  bf16*  proj_wb = (bf16*)(ws + 3801088);           //  1,179,648
  bf16*  fc1_wb  = (bf16*)(ws + 4980736);           //  4,718,592
  bf16*  fc2_wb  = (bf16*)(ws + 9699328);           //  4,718,592
  bf16*  ln1     = (bf16*)(ws + 14417920);          // 19,464,192 (MPAD x 768; reused: attn_o, ln2)
  bf16*  attn_o  = ln1;
  bf16*  ln2     = ln1;
  bf16*  qkvb    = (bf16*)(ws + 33882112);          // 77,856,768 (qkv MPADx2304; reused hbuf MPADx3072)
  bf16*  hbuf    = qkvb;
  bf16*  x2b     = (bf16*)(ws + 111738880);         // 19,464,192 (MPAD x 768 bf16) -> end 131,203,072

  cvt_kernel<<<(2304 * 768 + 255) / 256, 256, 0, stream>>>(qkv_w, qkv_wb, 2304 * 768);
  cvt_kernel<<<(768 * 768 + 255) / 256, 256, 0, stream>>>(proj_w, proj_wb, 768 * 768);
  cvt_kernel<<<(HID * 768 + 255) / 256, 256, 0, stream>>>(fc1_w, fc1_wb, HID * 768);
  cvt_kernel<<<(768 * HID + 255) / 256, 256, 0, stream>>>(fc2_w, fc2_wb, 768 * HID);

  la_pool_kernel<<<B * 49, 256, 0, stream>>>(x, f1_w, f1_b, f2_w, f2_b, v_w, v_b, fusion7);
  gate_ln1_kernel<<<B * N, 256, 0, stream>>>(x, fusion7, norm1_g, norm1_b, ln1);
  // qkv: (M x 768) x (2304 x 768)^T -> bf16
  gemm128<0, 768><<<dim3(2304 / 128, MPAD / 128), 256, 0, stream>>>(
      ln1, qkv_wb, qkv_b, nullptr, nullptr, qkvb, nullptr, 2304);
  attn_mfma_kernel<<<B * NH, 256, 0, stream>>>(qkvb, attn_o);
  // proj + residual(x f32) -> x2b (bf16)
  gemm128<0, 768><<<dim3(768 / 128, MPAD / 128), 256, 0, stream>>>(
      attn_o, proj_wb, proj_b, x, nullptr, x2b, nullptr, 768);
  ln_bf16_kernel<<<M, 256, 0, stream>>>(x2b, norm2_g, norm2_b, ln2);
  // fc1 + gelu -> hbuf (bf16)
  gemm128<1, 768><<<dim3(HID / 128, MPAD / 128), 256, 0, stream>>>(
      ln2, fc1_wb, fc1_b, nullptr, nullptr, hbuf, nullptr, HID);
  // fc2 + residual(x2b bf16) -> out (f32)
  gemm128<0, 3072><<<dim3(768 / 128, MPAD / 128), 256, 0, stream>>>(
      hbuf, fc2_wb, fc2_b, nullptr, x2b, nullptr, out, 768);
}

// Round 6
// 723.137 us; speedup vs baseline: 1.0733x; 1.0733x over previous
//
#include <hip/hip_runtime.h>
#include <hip/hip_bf16.h>
#include <math.h>

using bf16 = __hip_bfloat16;
using short8 = __attribute__((ext_vector_type(8))) short;
using floatx4 = __attribute__((ext_vector_type(4))) float;

constexpr int B = 64;
constexpr int N = 197;
constexpr int C = 768;
constexpr int NH = 12;
constexpr int HD = 64;
constexpr int HID = 3072;
constexpr int M = B * N;          // 12608 = 197 * 64
constexpr int MPAD = 12672;       // 99 * 128
constexpr float EPS = 1e-5f;

__device__ __forceinline__ float b2f(bf16 v) { return __bfloat162float(v); }
__device__ __forceinline__ bf16 f2b(float v) { return __float2bfloat16(v); }

// async global->LDS, 16B/lane. HW dest = wave-uniform base + lane*16.
typedef const __attribute__((address_space(1))) unsigned int* gas1_t;
typedef __attribute__((address_space(3))) unsigned int* las3_t;
__device__ __forceinline__ void load_lds16(const bf16* g, bf16* l) {
  __builtin_amdgcn_global_load_lds((gas1_t)g, (las3_t)l, 16, 0, 0);
}

// ---------------- f32 -> bf16 conversion (weights) -------------------------
__global__ void cvt_kernel(const float* __restrict__ src, bf16* __restrict__ dst, int n) {
  int i = blockIdx.x * 256 + threadIdx.x;
  if (i < n) dst[i] = f2b(src[i]);
}

// ---------------- block-wide sum over 256 threads (4 waves) ----------------
__device__ __forceinline__ float block_sum(float v, float* red) {
  #pragma unroll
  for (int off = 32; off >= 1; off >>= 1) v += __shfl_xor(v, off, 64);
  int w = threadIdx.x >> 6;
  if ((threadIdx.x & 63) == 0) red[w] = v;
  __syncthreads();
  float r = red[0] + red[1] + red[2] + red[3];
  __syncthreads();
  return r;
}

// ---------------- Kernel 1: LA pooling + channel MLP + fusion --------------
__global__ void la_pool_kernel(const float* __restrict__ x,
                               const float* __restrict__ f1w, const float* __restrict__ f1bias,
                               const float* __restrict__ f2w, const float* __restrict__ f2bias,
                               const float* __restrict__ vw,  const float* __restrict__ vbias,
                               float* __restrict__ fusion7) {
  int blk = blockIdx.x;
  int b = blk / 49, p = blk % 49;
  int h7 = p / 7, w7 = p % 7;
  int tid = threadIdx.x;
  int head = tid >> 4;     // 0..15
  int j = tid & 15;        // 0..15

  float sum = 0.f, mx = -3.0e38f;
  #pragma unroll
  for (int a = 0; a < 2; ++a) {
    #pragma unroll
    for (int bb = 0; bb < 2; ++bb) {
      int tok = 1 + (2 * h7 + a) * 14 + (2 * w7 + bb);
      const float* row = x + ((size_t)b * N + tok) * C + head * 48;
      #pragma unroll
      for (int s = 0; s < 3; ++s) {
        float v = row[j + 16 * s];
        sum += v;
        mx = fmaxf(mx, v);
      }
    }
  }
  #pragma unroll
  for (int off = 8; off >= 1; off >>= 1) {
    sum += __shfl_xor(sum, off, 64);
    mx = fmaxf(mx, __shfl_xor(mx, off, 64));
  }
  __shared__ float s_mean[16], s_max[16];
  if (j == 0) { s_mean[head] = sum / 192.f; s_max[head] = mx; }
  __syncthreads();
  if (tid < 16) {
    float hm = f1bias[0], hx = hm;
    #pragma unroll
    for (int h = 0; h < 16; ++h) {
      float w = f1w[h];
      hm += s_mean[h] * w;
      hx += s_max[h] * w;
    }
    hm = fmaxf(hm, 0.f);
    hx = fmaxf(hx, 0.f);
    float w2 = f2w[tid], b2v = f2bias[tid];
    float m   = hm * w2 + b2v;
    float mxv = hx * w2 + b2v;
    float fus = vw[0] * m + vw[1] * mxv + vbias[0];
    fusion7[((size_t)b * 16 + tid) * 49 + p] = fus;
  }
}

// ---------------- Kernel 2: gate (bilinear resize + sigmoid) + LN1 ---------
__global__ void gate_ln1_kernel(const float* __restrict__ x, const float* __restrict__ fusion7,
                                const float* __restrict__ g, const float* __restrict__ beta,
                                bf16* __restrict__ ln1) {
  int blk = blockIdx.x;
  int b = blk / N, n = blk % N;
  int tid = threadIdx.x;
  __shared__ float gates[16];
  __shared__ float red[4];

  if (tid < 16) {
    if (n > 0) {
      int hh = (n - 1) / 14, ww = (n - 1) % 14;
      float ch = fminf(fmaxf(hh * 0.5f - 0.25f, 0.f), 6.f);
      float cw = fminf(fmaxf(ww * 0.5f - 0.25f, 0.f), 6.f);
      int h0 = (int)floorf(ch); int h1 = min(h0 + 1, 6); float fh = ch - (float)h0;
      int w0 = (int)floorf(cw); int w1 = min(w0 + 1, 6); float fw = cw - (float)w0;
      const float* fp = fusion7 + ((size_t)b * 16 + tid) * 49;
      float v00 = fp[h0 * 7 + w0], v01 = fp[h0 * 7 + w1];
      float v10 = fp[h1 * 7 + w0], v11 = fp[h1 * 7 + w1];
      float v = (1.f - fh) * ((1.f - fw) * v00 + fw * v01)
              + fh        * ((1.f - fw) * v10 + fw * v11);
      gates[tid] = 1.f / (1.f + expf(-v));
    } else {
      gates[tid] = 0.f;   // cls token: multiplier (1+0) == identity
    }
  }
  __syncthreads();

  const float* xr = x + ((size_t)b * N + n) * C;
  float v[3];
  #pragma unroll
  for (int s = 0; s < 3; ++s) {
    int c = tid + 256 * s;
    v[s] = xr[c] * (1.f + gates[c / 48]);
  }
  float mu = block_sum(v[0] + v[1] + v[2], red) * (1.f / 768.f);
  float d0 = v[0] - mu, d1 = v[1] - mu, d2 = v[2] - mu;
  float var = block_sum(d0 * d0 + d1 * d1 + d2 * d2, red) * (1.f / 768.f);
  float rs = rsqrtf(var + EPS);
  bf16* orow = ln1 + ((size_t)b * N + n) * C;
  #pragma unroll
  for (int s = 0; s < 3; ++s) {
    int c = tid + 256 * s;
    orow[c] = f2b((v[s] - mu) * rs * g[c] + beta[c]);
  }
}

// ---------------- Kernel 3: LN over bf16 input -> bf16 ---------------------
__global__ void ln_bf16_kernel(const bf16* __restrict__ xin,
                               const float* __restrict__ g, const float* __restrict__ beta,
                               bf16* __restrict__ out) {
  int row = blockIdx.x;
  int tid = threadIdx.x;
  __shared__ float red[4];
  const bf16* xr = xin + (size_t)row * C;
  float v[3];
  #pragma unroll
  for (int s = 0; s < 3; ++s) v[s] = b2f(xr[tid + 256 * s]);
  float mu = block_sum(v[0] + v[1] + v[2], red) * (1.f / 768.f);
  float d0 = v[0] - mu, d1 = v[1] - mu, d2 = v[2] - mu;
  float var = block_sum(d0 * d0 + d1 * d1 + d2 * d2, red) * (1.f / 768.f);
  float rs = rsqrtf(var + EPS);
  bf16* orow = out + (size_t)row * C;
  #pragma unroll
  for (int s = 0; s < 3; ++s) {
    int c = tid + 256 * s;
    orow[c] = f2b((v[s] - mu) * rs * g[c] + beta[c]);
  }
}

// ---------------- Kernel 4: 128x128 tile, BK=32, double-buffered LDS -------
// C[M,Nc] = A[M,K]*W[Nc,K]^T + bias. EPI: 0=bias, 1=bias+exact gelu.
// Single barrier per K-iter: stage(k+1) issued right after the barrier that
// publishes buffer k, so its latency hides under compute(k).
// LDS chunk swizzle: slot seg at row r holds global chunk seg ^ ((r>>1)&3)
// -> fragment ds_read_b128 spreads 16 lanes over all 8 bank-groups (2-way, free).
// grid = (Nc/128, MPAD/128).
template <int EPI, int K>
__global__ void gemm128(const bf16* __restrict__ A, const bf16* __restrict__ W,
                        const float* __restrict__ bias,
                        const float* __restrict__ resF, const bf16* __restrict__ resB,
                        bf16* __restrict__ outB, float* __restrict__ outF, int Nc) {
  __shared__ __align__(16) bf16 sA[2][128 * 32];
  __shared__ __align__(16) bf16 sB[2][128 * 32];
  int tid = threadIdx.x;
  int wave = tid >> 6, lane = tid & 63, quad = lane >> 4, l16 = lane & 15;
  int m0 = blockIdx.y * 128;
  int n0 = blockIdx.x * 128;

  // staging: one issue = 16 rows x 64B. wave w covers rows w*32..w*32+31.
  int ln16 = lane >> 2, seg = lane & 3;
  int sw = seg ^ ((ln16 >> 1) & 3);                 // swizzled global chunk
  const bf16* gA = A + (size_t)(m0 + wave * 32 + ln16) * K + sw * 8;
  const bf16* gB = W + (size_t)(n0 + wave * 32 + ln16) * K + sw * 8;

  int wm = (wave & 1) * 64, wn = (wave >> 1) * 64;  // wave quadrant
  int csw = (l16 >> 1) & 3;                         // fragment-read swizzle
  floatx4 acc[4][4] = {};

  // prologue: stage k0=0 into buffer 0
  #pragma unroll
  for (int i = 0; i < 2; ++i) {
    load_lds16(gA + (size_t)(i * 16) * K, &sA[0][(wave * 32 + i * 16) * 32]);
    load_lds16(gB + (size_t)(i * 16) * K, &sB[0][(wave * 32 + i * 16) * 32]);
  }

  int p = 0;
  for (int k0 = 0; k0 < K; k0 += 32, p ^= 1) {
    __syncthreads();                    // publishes buffer p (drains vmcnt)
    if (k0 + 32 < K) {                  // prefetch k+1 into buffer p^1
      #pragma unroll
      for (int i = 0; i < 2; ++i) {
        load_lds16(gA + (size_t)(i * 16) * K + (k0 + 32), &sA[p ^ 1][(wave * 32 + i * 16) * 32]);
        load_lds16(gB + (size_t)(i * 16) * K + (k0 + 32), &sB[p ^ 1][(wave * 32 + i * 16) * 32]);
      }
    }
    short8 af[4], bw[4];
    #pragma unroll
    for (int s = 0; s < 4; ++s) {
      int row = wm + s * 16 + l16;
      af[s] = *reinterpret_cast<const short8*>(&sA[p][row * 32 + ((quad ^ csw) * 8)]);
    }
    #pragma unroll
    for (int t = 0; t < 4; ++t) {
      int row = wn + t * 16 + l16;
      bw[t] = *reinterpret_cast<const short8*>(&sB[p][row * 32 + ((quad ^ csw) * 8)]);
    }
    #pragma unroll
    for (int s = 0; s < 4; ++s)
      #pragma unroll
      for (int t = 0; t < 4; ++t)
        acc[s][t] = __builtin_amdgcn_mfma_f32_16x16x32_bf16(af[s], bw[t], acc[s][t], 0, 0, 0);
  }

  #pragma unroll
  for (int t = 0; t < 4; ++t) {
    int col = n0 + wn + t * 16 + l16;
    float bv = bias[col];
    #pragma unroll
    for (int s = 0; s < 4; ++s) {
      int rowb = m0 + wm + s * 16 + quad * 4;
      #pragma unroll
      for (int r = 0; r < 4; ++r) {
        int row = rowb + r;
        if (row < M) {
          float v = acc[s][t][r] + bv;
          if (EPI == 1) v = 0.5f * v * (1.f + erff(v * 0.7071067811865475f));
          size_t idx = (size_t)row * Nc + col;
          if (resF) v += resF[idx];
          if (resB) v += b2f(resB[idx]);
          if (outF) outF[idx] = v;
          if (outB) outB[idx] = f2b(v);
        }
      }
    }
  }
}

// ---------------- Kernel 5: MFMA attention, one block per (b, head) --------
__global__ void attn_mfma_kernel(const bf16* __restrict__ qkv, bf16* __restrict__ attn_o) {
  int bh = blockIdx.x;
  int h = bh % NH, b = bh / NH;
  int tid = threadIdx.x;
  int wave = tid >> 6, lane = tid & 63, quad = lane >> 4, l16 = lane & 15;

  __shared__ __align__(16) bf16 sVt[64][232];     // V^T: [d][m], m>=197 zero
  __shared__ __align__(16) bf16 sP[4][16][232];   // per-wave P: [q][m]

  const bf16* base = qkv + (size_t)b * N * 2304 + h * 64;

  {
    int d = tid & 63;
    for (int m = tid >> 6; m < 224; m += 4) {
      sVt[d][m] = (m < N) ? base[(size_t)m * 2304 + 1536 + d] : f2b(0.f);
    }
  }
  __syncthreads();

  const float scale = 0.125f;   // 64^-0.5

  for (int qt = wave; qt < 13; qt += 4) {
    int qr = min(qt * 16 + l16, N - 1);
    const bf16* qp = base + (size_t)qr * 2304;
    short8 aq0 = *reinterpret_cast<const short8*>(qp + quad * 8);
    short8 aq1 = *reinterpret_cast<const short8*>(qp + 32 + quad * 8);

    floatx4 s[13];
    #pragma unroll
    for (int kt = 0; kt < 13; ++kt) {
      int kr = min(kt * 16 + l16, N - 1);
      const bf16* kp = base + (size_t)kr * 2304 + 768;
      short8 bk0 = *reinterpret_cast<const short8*>(kp + quad * 8);
      short8 bk1 = *reinterpret_cast<const short8*>(kp + 32 + quad * 8);
      floatx4 acc = floatx4{0.f, 0.f, 0.f, 0.f};
      acc = __builtin_amdgcn_mfma_f32_16x16x32_bf16(aq0, bk0, acc, 0, 0, 0);
      acc = __builtin_amdgcn_mfma_f32_16x16x32_bf16(aq1, bk1, acc, 0, 0, 0);
      s[kt] = acc;
    }

    bool cv[13];
    #pragma unroll
    for (int kt = 0; kt < 13; ++kt) cv[kt] = (kt * 16 + l16) < N;

    float mx[4] = {-3.0e38f, -3.0e38f, -3.0e38f, -3.0e38f};
    #pragma unroll
    for (int kt = 0; kt < 13; ++kt) {
      #pragma unroll
      for (int r = 0; r < 4; ++r) {
        float sv = s[kt][r] * scale;
        s[kt][r] = sv;
        if (cv[kt]) mx[r] = fmaxf(mx[r], sv);
      }
    }
    #pragma unroll
    for (int off = 8; off >= 1; off >>= 1) {
      #pragma unroll
      for (int r = 0; r < 4; ++r) mx[r] = fmaxf(mx[r], __shfl_xor(mx[r], off, 64));
    }
    float sum[4] = {0.f, 0.f, 0.f, 0.f};
    #pragma unroll
    for (int kt = 0; kt < 13; ++kt) {
      #pragma unroll
      for (int r = 0; r < 4; ++r) {
        float e = cv[kt] ? expf(s[kt][r] - mx[r]) : 0.f;
        s[kt][r] = e;
        sum[r] += e;
      }
    }
    #pragma unroll
    for (int off = 8; off >= 1; off >>= 1) {
      #pragma unroll
      for (int r = 0; r < 4; ++r) sum[r] += __shfl_xor(sum[r], off, 64);
    }
    float inv[4];
    #pragma unroll
    for (int r = 0; r < 4; ++r) inv[r] = 1.f / sum[r];

    #pragma unroll
    for (int kt = 0; kt < 13; ++kt) {
      #pragma unroll
      for (int r = 0; r < 4; ++r)
        sP[wave][quad * 4 + r][kt * 16 + l16] = f2b(s[kt][r]);
    }
    #pragma unroll
    for (int r = 0; r < 4; ++r)
      sP[wave][quad * 4 + r][208 + l16] = f2b(0.f);

    floatx4 o[4] = {floatx4{0,0,0,0}, floatx4{0,0,0,0}, floatx4{0,0,0,0}, floatx4{0,0,0,0}};
    #pragma unroll
    for (int c = 0; c < 7; ++c) {
      short8 ap = *reinterpret_cast<const short8*>(&sP[wave][l16][c * 32 + quad * 8]);
      #pragma unroll
      for (int t = 0; t < 4; ++t) {
        short8 bv = *reinterpret_cast<const short8*>(&sVt[t * 16 + l16][c * 32 + quad * 8]);
        o[t] = __builtin_amdgcn_mfma_f32_16x16x32_bf16(ap, bv, o[t], 0, 0, 0);
      }
    }

    #pragma unroll
    for (int t = 0; t < 4; ++t) {
      #pragma unroll
      for (int r = 0; r < 4; ++r) {
        int qrow = qt * 16 + quad * 4 + r;
        if (qrow < N)
          attn_o[((size_t)b * N + qrow) * C + h * 64 + t * 16 + l16] = f2b(o[t][r] * inv[r]);
      }
    }
  }
}

// ---------------- host-side orchestration ----------------------------------
extern "C" void kernel_launch(void* const* d_in, const int* in_sizes, int n_in,
                              void* d_out, int out_size, void* d_ws, size_t ws_size,
                              hipStream_t stream) {
  (void)in_sizes; (void)n_in; (void)out_size; (void)ws_size;
  const float* x       = (const float*)d_in[0];
  const float* norm1_g = (const float*)d_in[1];
  const float* norm1_b = (const float*)d_in[2];
  const float* qkv_w   = (const float*)d_in[3];
  const float* qkv_b   = (const float*)d_in[4];
  const float* proj_w  = (const float*)d_in[5];
  const float* proj_b  = (const float*)d_in[6];
  const float* norm2_g = (const float*)d_in[7];
  const float* norm2_b = (const float*)d_in[8];
  const float* fc1_w   = (const float*)d_in[9];
  const float* fc1_b   = (const float*)d_in[10];
  const float* fc2_w   = (const float*)d_in[11];
  const float* fc2_b   = (const float*)d_in[12];
  const float* f1_w    = (const float*)d_in[13];
  const float* f1_b    = (const float*)d_in[14];
  const float* f2_w    = (const float*)d_in[15];
  const float* f2_b    = (const float*)d_in[16];
  const float* v_w     = (const float*)d_in[17];
  const float* v_b     = (const float*)d_in[18];
  float* out = (float*)d_out;

  char* ws = (char*)d_ws;
  // ws layout (~131.2 MB). Activation buffers padded to MPAD=12672 rows.
  float* fusion7 = (float*)(ws + 0);                //    200,704
  bf16*  qkv_wb  = (bf16*)(ws + 262144);            //  3,538,944
  bf16*  proj_wb = (bf16*)(ws + 3801088);           //  1,179,648
  bf16*  fc1_wb  = (bf16*)(ws + 4980736);           //  4,718,592
  bf16*  fc2_wb  = (bf16*)(ws + 9699328);           //  4,718,592
  bf16*  ln1     = (bf16*)(ws + 14417920);          // 19,464,192 (MPAD x 768; reused: attn_o, ln2)
  bf16*  attn_o  = ln1;
  bf16*  ln2     = ln1;
  bf16*  qkvb    = (bf16*)(ws + 33882112);          // 77,856,768 (qkv MPADx2304; reused hbuf MPADx3072)
  bf16*  hbuf    = qkvb;
  bf16*  x2b     = (bf16*)(ws + 111738880);         // 19,464,192 (MPAD x 768 bf16) -> end 131,203,072

  cvt_kernel<<<(2304 * 768 + 255) / 256, 256, 0, stream>>>(qkv_w, qkv_wb, 2304 * 768);
  cvt_kernel<<<(768 * 768 + 255) / 256, 256, 0, stream>>>(proj_w, proj_wb, 768 * 768);
  cvt_kernel<<<(HID * 768 + 255) / 256, 256, 0, stream>>>(fc1_w, fc1_wb, HID * 768);
  cvt_kernel<<<(768 * HID + 255) / 256, 256, 0, stream>>>(fc2_w, fc2_wb, 768 * HID);

  la_pool_kernel<<<B * 49, 256, 0, stream>>>(x, f1_w, f1_b, f2_w, f2_b, v_w, v_b, fusion7);
  gate_ln1_kernel<<<B * N, 256, 0, stream>>>(x, fusion7, norm1_g, norm1_b, ln1);
  // qkv: (M x 768) x (2304 x 768)^T -> bf16
  gemm128<0, 768><<<dim3(2304 / 128, MPAD / 128), 256, 0, stream>>>(
      ln1, qkv_wb, qkv_b, nullptr, nullptr, qkvb, nullptr, 2304);
  attn_mfma_kernel<<<B * NH, 256, 0, stream>>>(qkvb, attn_o);
  // proj + residual(x f32) -> x2b (bf16)
  gemm128<0, 768><<<dim3(768 / 128, MPAD / 128), 256, 0, stream>>>(
      attn_o, proj_wb, proj_b, x, nullptr, x2b, nullptr, 768);
  ln_bf16_kernel<<<M, 256, 0, stream>>>(x2b, norm2_g, norm2_b, ln2);
  // fc1 + gelu -> hbuf (bf16)
  gemm128<1, 768><<<dim3(HID / 128, MPAD / 128), 256, 0, stream>>>(
      ln2, fc1_wb, fc1_b, nullptr, nullptr, hbuf, nullptr, HID);
  // fc2 + residual(x2b bf16) -> out (f32)
  gemm128<0, 3072><<<dim3(768 / 128, MPAD / 128), 256, 0, stream>>>(
      hbuf, fc2_wb, fc2_b, nullptr, x2b, nullptr, out, 768);
}

// Round 7
// 707.189 us; speedup vs baseline: 1.0975x; 1.0226x over previous
//
#include <hip/hip_runtime.h>
#include <hip/hip_bf16.h>
#include <math.h>

using bf16 = __hip_bfloat16;
using short8 = __attribute__((ext_vector_type(8))) short;
using floatx4 = __attribute__((ext_vector_type(4))) float;

constexpr int B = 64;
constexpr int N = 197;
constexpr int C = 768;
constexpr int NH = 12;
constexpr int HD = 64;
constexpr int HID = 3072;
constexpr int M = B * N;          // 12608 = 197 * 64
constexpr int MPAD = 12672;       // 99 * 128
constexpr int MT = MPAD / 128;    // 99 M-tiles
constexpr int MTP = 104;          // padded to 8*13 for XCD swizzle
constexpr float EPS = 1e-5f;

__device__ __forceinline__ float b2f(bf16 v) { return __bfloat162float(v); }
__device__ __forceinline__ bf16 f2b(float v) { return __float2bfloat16(v); }

// async global->LDS, 16B/lane. HW dest = wave-uniform base + lane*16.
typedef const __attribute__((address_space(1))) unsigned int* gas1_t;
typedef __attribute__((address_space(3))) unsigned int* las3_t;
__device__ __forceinline__ void load_lds16(const bf16* g, bf16* l) {
  __builtin_amdgcn_global_load_lds((gas1_t)g, (las3_t)l, 16, 0, 0);
}

// ---------------- f32 -> bf16 conversion (weights) -------------------------
__global__ void cvt_kernel(const float* __restrict__ src, bf16* __restrict__ dst, int n) {
  int i = blockIdx.x * 256 + threadIdx.x;
  if (i < n) dst[i] = f2b(src[i]);
}

// ---------------- block-wide sum over 256 threads (4 waves) ----------------
__device__ __forceinline__ float block_sum(float v, float* red) {
  #pragma unroll
  for (int off = 32; off >= 1; off >>= 1) v += __shfl_xor(v, off, 64);
  int w = threadIdx.x >> 6;
  if ((threadIdx.x & 63) == 0) red[w] = v;
  __syncthreads();
  float r = red[0] + red[1] + red[2] + red[3];
  __syncthreads();
  return r;
}

// ---------------- Kernel 1: LA pooling + channel MLP + fusion --------------
__global__ void la_pool_kernel(const float* __restrict__ x,
                               const float* __restrict__ f1w, const float* __restrict__ f1bias,
                               const float* __restrict__ f2w, const float* __restrict__ f2bias,
                               const float* __restrict__ vw,  const float* __restrict__ vbias,
                               float* __restrict__ fusion7) {
  int blk = blockIdx.x;
  int b = blk / 49, p = blk % 49;
  int h7 = p / 7, w7 = p % 7;
  int tid = threadIdx.x;
  int head = tid >> 4;     // 0..15
  int j = tid & 15;        // 0..15

  float sum = 0.f, mx = -3.0e38f;
  #pragma unroll
  for (int a = 0; a < 2; ++a) {
    #pragma unroll
    for (int bb = 0; bb < 2; ++bb) {
      int tok = 1 + (2 * h7 + a) * 14 + (2 * w7 + bb);
      const float* row = x + ((size_t)b * N + tok) * C + head * 48;
      #pragma unroll
      for (int s = 0; s < 3; ++s) {
        float v = row[j + 16 * s];
        sum += v;
        mx = fmaxf(mx, v);
      }
    }
  }
  #pragma unroll
  for (int off = 8; off >= 1; off >>= 1) {
    sum += __shfl_xor(sum, off, 64);
    mx = fmaxf(mx, __shfl_xor(mx, off, 64));
  }
  __shared__ float s_mean[16], s_max[16];
  if (j == 0) { s_mean[head] = sum / 192.f; s_max[head] = mx; }
  __syncthreads();
  if (tid < 16) {
    float hm = f1bias[0], hx = hm;
    #pragma unroll
    for (int h = 0; h < 16; ++h) {
      float w = f1w[h];
      hm += s_mean[h] * w;
      hx += s_max[h] * w;
    }
    hm = fmaxf(hm, 0.f);
    hx = fmaxf(hx, 0.f);
    float w2 = f2w[tid], b2v = f2bias[tid];
    float m   = hm * w2 + b2v;
    float mxv = hx * w2 + b2v;
    float fus = vw[0] * m + vw[1] * mxv + vbias[0];
    fusion7[((size_t)b * 16 + tid) * 49 + p] = fus;
  }
}

// ---------------- Kernel 2: gate (bilinear resize + sigmoid) + LN1 ---------
__global__ void gate_ln1_kernel(const float* __restrict__ x, const float* __restrict__ fusion7,
                                const float* __restrict__ g, const float* __restrict__ beta,
                                bf16* __restrict__ ln1) {
  int blk = blockIdx.x;
  int b = blk / N, n = blk % N;
  int tid = threadIdx.x;
  __shared__ float gates[16];
  __shared__ float red[4];

  if (tid < 16) {
    if (n > 0) {
      int hh = (n - 1) / 14, ww = (n - 1) % 14;
      float ch = fminf(fmaxf(hh * 0.5f - 0.25f, 0.f), 6.f);
      float cw = fminf(fmaxf(ww * 0.5f - 0.25f, 0.f), 6.f);
      int h0 = (int)floorf(ch); int h1 = min(h0 + 1, 6); float fh = ch - (float)h0;
      int w0 = (int)floorf(cw); int w1 = min(w0 + 1, 6); float fw = cw - (float)w0;
      const float* fp = fusion7 + ((size_t)b * 16 + tid) * 49;
      float v00 = fp[h0 * 7 + w0], v01 = fp[h0 * 7 + w1];
      float v10 = fp[h1 * 7 + w0], v11 = fp[h1 * 7 + w1];
      float v = (1.f - fh) * ((1.f - fw) * v00 + fw * v01)
              + fh        * ((1.f - fw) * v10 + fw * v11);
      gates[tid] = 1.f / (1.f + expf(-v));
    } else {
      gates[tid] = 0.f;   // cls token: multiplier (1+0) == identity
    }
  }
  __syncthreads();

  const float* xr = x + ((size_t)b * N + n) * C;
  float v[3];
  #pragma unroll
  for (int s = 0; s < 3; ++s) {
    int c = tid + 256 * s;
    v[s] = xr[c] * (1.f + gates[c / 48]);
  }
  float mu = block_sum(v[0] + v[1] + v[2], red) * (1.f / 768.f);
  float d0 = v[0] - mu, d1 = v[1] - mu, d2 = v[2] - mu;
  float var = block_sum(d0 * d0 + d1 * d1 + d2 * d2, red) * (1.f / 768.f);
  float rs = rsqrtf(var + EPS);
  bf16* orow = ln1 + ((size_t)b * N + n) * C;
  #pragma unroll
  for (int s = 0; s < 3; ++s) {
    int c = tid + 256 * s;
    orow[c] = f2b((v[s] - mu) * rs * g[c] + beta[c]);
  }
}

// ---------------- Kernel 3: LN over bf16 input -> bf16 ---------------------
__global__ void ln_bf16_kernel(const bf16* __restrict__ xin,
                               const float* __restrict__ g, const float* __restrict__ beta,
                               bf16* __restrict__ out) {
  int row = blockIdx.x;
  int tid = threadIdx.x;
  __shared__ float red[4];
  const bf16* xr = xin + (size_t)row * C;
  float v[3];
  #pragma unroll
  for (int s = 0; s < 3; ++s) v[s] = b2f(xr[tid + 256 * s]);
  float mu = block_sum(v[0] + v[1] + v[2], red) * (1.f / 768.f);
  float d0 = v[0] - mu, d1 = v[1] - mu, d2 = v[2] - mu;
  float var = block_sum(d0 * d0 + d1 * d1 + d2 * d2, red) * (1.f / 768.f);
  float rs = rsqrtf(var + EPS);
  bf16* orow = out + (size_t)row * C;
  #pragma unroll
  for (int s = 0; s < 3; ++s) {
    int c = tid + 256 * s;
    orow[c] = f2b((v[s] - mu) * rs * g[c] + beta[c]);
  }
}

// ---------------- Kernel 4: 128x128 tile, BK=32, dbuf, XCD-swizzled grid ---
// C[M,Nc] = A[M,K]*W[Nc,K]^T + bias. EPI: 0=bias, 1=bias+exact gelu.
// 1-D grid of nx*104 blocks. Block g serves XCD g&7 (dispatch round-robin
// heuristic); XCD c owns M-tile rows y = c + 8*j, sweeping N-tiles x fastest,
// so all x-partners of an A-row-group run on one XCD -> A staged from that
// XCD's L2 instead of 6-18x from L3.
template <int EPI, int K>
__global__ void gemm128(const bf16* __restrict__ A, const bf16* __restrict__ W,
                        const float* __restrict__ bias,
                        const float* __restrict__ resF, const bf16* __restrict__ resB,
                        bf16* __restrict__ outB, float* __restrict__ outF, int Nc) {
  int nx = Nc >> 7;
  {
  }
  int g = blockIdx.x;
  int c = g & 7, t = g >> 3;
  int x = t % nx;
  int y = c + 8 * (t / nx);
  if (y >= MT) return;                 // padded tail (y in [99,104))
  int m0 = y * 128;
  int n0 = x * 128;

  __shared__ __align__(16) bf16 sA[2][128 * 32];
  __shared__ __align__(16) bf16 sB[2][128 * 32];
  int tid = threadIdx.x;
  int wave = tid >> 6, lane = tid & 63, quad = lane >> 4, l16 = lane & 15;

  // staging: one issue = 16 rows x 64B. wave w covers rows w*32..w*32+31.
  int ln16 = lane >> 2, seg = lane & 3;
  int sw = seg ^ ((ln16 >> 1) & 3);                 // swizzled global chunk
  const bf16* gA = A + (size_t)(m0 + wave * 32 + ln16) * K + sw * 8;
  const bf16* gB = W + (size_t)(n0 + wave * 32 + ln16) * K + sw * 8;

  int wm = (wave & 1) * 64, wn = (wave >> 1) * 64;  // wave quadrant
  int csw = (l16 >> 1) & 3;                         // fragment-read swizzle
  floatx4 acc[4][4] = {};

  // prologue: stage k0=0 into buffer 0
  #pragma unroll
  for (int i = 0; i < 2; ++i) {
    load_lds16(gA + (size_t)(i * 16) * K, &sA[0][(wave * 32 + i * 16) * 32]);
    load_lds16(gB + (size_t)(i * 16) * K, &sB[0][(wave * 32 + i * 16) * 32]);
  }

  int p = 0;
  for (int k0 = 0; k0 < K; k0 += 32, p ^= 1) {
    __syncthreads();                    // publishes buffer p
    if (k0 + 32 < K) {                  // prefetch k+1 into buffer p^1
      #pragma unroll
      for (int i = 0; i < 2; ++i) {
        load_lds16(gA + (size_t)(i * 16) * K + (k0 + 32), &sA[p ^ 1][(wave * 32 + i * 16) * 32]);
        load_lds16(gB + (size_t)(i * 16) * K + (k0 + 32), &sB[p ^ 1][(wave * 32 + i * 16) * 32]);
      }
    }
    short8 af[4], bw[4];
    #pragma unroll
    for (int s = 0; s < 4; ++s) {
      int row = wm + s * 16 + l16;
      af[s] = *reinterpret_cast<const short8*>(&sA[p][row * 32 + ((quad ^ csw) * 8)]);
    }
    #pragma unroll
    for (int t2 = 0; t2 < 4; ++t2) {
      int row = wn + t2 * 16 + l16;
      bw[t2] = *reinterpret_cast<const short8*>(&sB[p][row * 32 + ((quad ^ csw) * 8)]);
    }
    #pragma unroll
    for (int s = 0; s < 4; ++s)
      #pragma unroll
      for (int t2 = 0; t2 < 4; ++t2)
        acc[s][t2] = __builtin_amdgcn_mfma_f32_16x16x32_bf16(af[s], bw[t2], acc[s][t2], 0, 0, 0);
  }

  #pragma unroll
  for (int t2 = 0; t2 < 4; ++t2) {
    int col = n0 + wn + t2 * 16 + l16;
    float bv = bias[col];
    #pragma unroll
    for (int s = 0; s < 4; ++s) {
      int rowb = m0 + wm + s * 16 + quad * 4;
      #pragma unroll
      for (int r = 0; r < 4; ++r) {
        int row = rowb + r;
        if (row < M) {
          float v = acc[s][t2][r] + bv;
          if (EPI == 1) v = 0.5f * v * (1.f + erff(v * 0.7071067811865475f));
          size_t idx = (size_t)row * Nc + col;
          if (resF) v += resF[idx];
          if (resB) v += b2f(resB[idx]);
          if (outF) outF[idx] = v;
          if (outB) outB[idx] = f2b(v);
        }
      }
    }
  }
}

// ---------------- Kernel 5: MFMA attention, one block per (b, head) --------
__global__ void attn_mfma_kernel(const bf16* __restrict__ qkv, bf16* __restrict__ attn_o) {
  int bh = blockIdx.x;
  int h = bh % NH, b = bh / NH;
  int tid = threadIdx.x;
  int wave = tid >> 6, lane = tid & 63, quad = lane >> 4, l16 = lane & 15;

  __shared__ __align__(16) bf16 sVt[64][232];     // V^T: [d][m], m>=197 zero
  __shared__ __align__(16) bf16 sP[4][16][232];   // per-wave P: [q][m]

  const bf16* base = qkv + (size_t)b * N * 2304 + h * 64;

  {
    int d = tid & 63;
    for (int m = tid >> 6; m < 224; m += 4) {
      sVt[d][m] = (m < N) ? base[(size_t)m * 2304 + 1536 + d] : f2b(0.f);
    }
  }
  __syncthreads();

  const float scale = 0.125f;   // 64^-0.5

  for (int qt = wave; qt < 13; qt += 4) {
    int qr = min(qt * 16 + l16, N - 1);
    const bf16* qp = base + (size_t)qr * 2304;
    short8 aq0 = *reinterpret_cast<const short8*>(qp + quad * 8);
    short8 aq1 = *reinterpret_cast<const short8*>(qp + 32 + quad * 8);

    floatx4 s[13];
    #pragma unroll
    for (int kt = 0; kt < 13; ++kt) {
      int kr = min(kt * 16 + l16, N - 1);
      const bf16* kp = base + (size_t)kr * 2304 + 768;
      short8 bk0 = *reinterpret_cast<const short8*>(kp + quad * 8);
      short8 bk1 = *reinterpret_cast<const short8*>(kp + 32 + quad * 8);
      floatx4 acc = floatx4{0.f, 0.f, 0.f, 0.f};
      acc = __builtin_amdgcn_mfma_f32_16x16x32_bf16(aq0, bk0, acc, 0, 0, 0);
      acc = __builtin_amdgcn_mfma_f32_16x16x32_bf16(aq1, bk1, acc, 0, 0, 0);
      s[kt] = acc;
    }

    bool cv[13];
    #pragma unroll
    for (int kt = 0; kt < 13; ++kt) cv[kt] = (kt * 16 + l16) < N;

    float mx[4] = {-3.0e38f, -3.0e38f, -3.0e38f, -3.0e38f};
    #pragma unroll
    for (int kt = 0; kt < 13; ++kt) {
      #pragma unroll
      for (int r = 0; r < 4; ++r) {
        float sv = s[kt][r] * scale;
        s[kt][r] = sv;
        if (cv[kt]) mx[r] = fmaxf(mx[r], sv);
      }
    }
    #pragma unroll
    for (int off = 8; off >= 1; off >>= 1) {
      #pragma unroll
      for (int r = 0; r < 4; ++r) mx[r] = fmaxf(mx[r], __shfl_xor(mx[r], off, 64));
    }
    float sum[4] = {0.f, 0.f, 0.f, 0.f};
    #pragma unroll
    for (int kt = 0; kt < 13; ++kt) {
      #pragma unroll
      for (int r = 0; r < 4; ++r) {
        float e = cv[kt] ? expf(s[kt][r] - mx[r]) : 0.f;
        s[kt][r] = e;
        sum[r] += e;
      }
    }
    #pragma unroll
    for (int off = 8; off >= 1; off >>= 1) {
      #pragma unroll
      for (int r = 0; r < 4; ++r) sum[r] += __shfl_xor(sum[r], off, 64);
    }
    float inv[4];
    #pragma unroll
    for (int r = 0; r < 4; ++r) inv[r] = 1.f / sum[r];

    #pragma unroll
    for (int kt = 0; kt < 13; ++kt) {
      #pragma unroll
      for (int r = 0; r < 4; ++r)
        sP[wave][quad * 4 + r][kt * 16 + l16] = f2b(s[kt][r]);
    }
    #pragma unroll
    for (int r = 0; r < 4; ++r)
      sP[wave][quad * 4 + r][208 + l16] = f2b(0.f);

    floatx4 o[4] = {floatx4{0,0,0,0}, floatx4{0,0,0,0}, floatx4{0,0,0,0}, floatx4{0,0,0,0}};
    #pragma unroll
    for (int c = 0; c < 7; ++c) {
      short8 ap = *reinterpret_cast<const short8*>(&sP[wave][l16][c * 32 + quad * 8]);
      #pragma unroll
      for (int t = 0; t < 4; ++t) {
        short8 bv = *reinterpret_cast<const short8*>(&sVt[t * 16 + l16][c * 32 + quad * 8]);
        o[t] = __builtin_amdgcn_mfma_f32_16x16x32_bf16(ap, bv, o[t], 0, 0, 0);
      }
    }

    #pragma unroll
    for (int t = 0; t < 4; ++t) {
      #pragma unroll
      for (int r = 0; r < 4; ++r) {
        int qrow = qt * 16 + quad * 4 + r;
        if (qrow < N)
          attn_o[((size_t)b * N + qrow) * C + h * 64 + t * 16 + l16] = f2b(o[t][r] * inv[r]);
      }
    }
  }
}

// ---------------- host-side orchestration ----------------------------------
extern "C" void kernel_launch(void* const* d_in, const int* in_sizes, int n_in,
                              void* d_out, int out_size, void* d_ws, size_t ws_size,
                              hipStream_t stream) {
  (void)in_sizes; (void)n_in; (void)out_size; (void)ws_size;
  const float* x       = (const float*)d_in[0];
  const float* norm1_g = (const float*)d_in[1];
  const float* norm1_b = (const float*)d_in[2];
  const float* qkv_w   = (const float*)d_in[3];
  const float* qkv_b   = (const float*)d_in[4];
  const float* proj_w  = (const float*)d_in[5];
  const float* proj_b  = (const float*)d_in[6];
  const float* norm2_g = (const float*)d_in[7];
  const float* norm2_b = (const float*)d_in[8];
  const float* fc1_w   = (const float*)d_in[9];
  const float* fc1_b   = (const float*)d_in[10];
  const float* fc2_w   = (const float*)d_in[11];
  const float* fc2_b   = (const float*)d_in[12];
  const float* f1_w    = (const float*)d_in[13];
  const float* f1_b    = (const float*)d_in[14];
  const float* f2_w    = (const float*)d_in[15];
  const float* f2_b    = (const float*)d_in[16];
  const float* v_w     = (const float*)d_in[17];
  const float* v_b     = (const float*)d_in[18];
  float* out = (float*)d_out;

  char* ws = (char*)d_ws;
  // ws layout (~131.2 MB). Activation buffers padded to MPAD=12672 rows.
  float* fusion7 = (float*)(ws + 0);                //    200,704
  bf16*  qkv_wb  = (bf16*)(ws + 262144);            //  3,538,944
  bf16*  proj_wb = (bf16*)(ws + 3801088);           //  1,179,648
  bf16*  fc1_wb  = (bf16*)(ws + 4980736);           //  4,718,592
  bf16*  fc2_wb  = (bf16*)(ws + 9699328);           //  4,718,592
  bf16*  ln1     = (bf16*)(ws + 14417920);          // 19,464,192 (MPAD x 768; reused: attn_o, ln2)
  bf16*  attn_o  = ln1;
  bf16*  ln2     = ln1;
  bf16*  qkvb    = (bf16*)(ws + 33882112);          // 77,856,768 (qkv MPADx2304; reused hbuf MPADx3072)
  bf16*  hbuf    = qkvb;
  bf16*  x2b     = (bf16*)(ws + 111738880);         // 19,464,192 (MPAD x 768 bf16) -> end 131,203,072

  cvt_kernel<<<(2304 * 768 + 255) / 256, 256, 0, stream>>>(qkv_w, qkv_wb, 2304 * 768);
  cvt_kernel<<<(768 * 768 + 255) / 256, 256, 0, stream>>>(proj_w, proj_wb, 768 * 768);
  cvt_kernel<<<(HID * 768 + 255) / 256, 256, 0, stream>>>(fc1_w, fc1_wb, HID * 768);
  cvt_kernel<<<(768 * HID + 255) / 256, 256, 0, stream>>>(fc2_w, fc2_wb, 768 * HID);

  la_pool_kernel<<<B * 49, 256, 0, stream>>>(x, f1_w, f1_b, f2_w, f2_b, v_w, v_b, fusion7);
  gate_ln1_kernel<<<B * N, 256, 0, stream>>>(x, fusion7, norm1_g, norm1_b, ln1);
  // qkv: (M x 768) x (2304 x 768)^T -> bf16
  gemm128<0, 768><<<(2304 / 128) * MTP, 256, 0, stream>>>(
      ln1, qkv_wb, qkv_b, nullptr, nullptr, qkvb, nullptr, 2304);
  attn_mfma_kernel<<<B * NH, 256, 0, stream>>>(qkvb, attn_o);
  // proj + residual(x f32) -> x2b (bf16)
  gemm128<0, 768><<<(768 / 128) * MTP, 256, 0, stream>>>(
      attn_o, proj_wb, proj_b, x, nullptr, x2b, nullptr, 768);
  ln_bf16_kernel<<<M, 256, 0, stream>>>(x2b, norm2_g, norm2_b, ln2);
  // fc1 + gelu -> hbuf (bf16)
  gemm128<1, 768><<<(HID / 128) * MTP, 256, 0, stream>>>(
      ln2, fc1_wb, fc1_b, nullptr, nullptr, hbuf, nullptr, HID);
  // fc2 + residual(x2b bf16) -> out (f32)
  gemm128<0, 3072><<<(768 / 128) * MTP, 256, 0, stream>>>(
      hbuf, fc2_wb, fc2_b, nullptr, x2b, nullptr, out, 768);
}

// Round 8
// 695.645 us; speedup vs baseline: 1.1157x; 1.0166x over previous
//
#include <hip/hip_runtime.h>
#include <hip/hip_bf16.h>
#include <math.h>

using bf16 = __hip_bfloat16;
using short8 = __attribute__((ext_vector_type(8))) short;
using floatx4 = __attribute__((ext_vector_type(4))) float;

constexpr int B = 64;
constexpr int N = 197;
constexpr int C = 768;
constexpr int NH = 12;
constexpr int HD = 64;
constexpr int HID = 3072;
constexpr int M = B * N;          // 12608 = 197 * 64
constexpr int MPAD = 12672;       // 99 * 128
constexpr int MT = MPAD / 128;    // 99 M-tiles
constexpr int MTP = 104;          // padded to 8*13 for XCD swizzle
constexpr float EPS = 1e-5f;

__device__ __forceinline__ float b2f(bf16 v) { return __bfloat162float(v); }
__device__ __forceinline__ bf16 f2b(float v) { return __float2bfloat16(v); }

// async global->LDS, 16B/lane. HW dest = wave-uniform base + lane*16.
typedef const __attribute__((address_space(1))) unsigned int* gas1_t;
typedef __attribute__((address_space(3))) unsigned int* las3_t;
__device__ __forceinline__ void load_lds16(const bf16* g, bf16* l) {
  __builtin_amdgcn_global_load_lds((gas1_t)g, (las3_t)l, 16, 0, 0);
}

// ------- f32 weights -> bf16 MFMA-fragment layout --------------------------
// Wf[nb][kc][t'][lane*8]: slab of 512 bf16 = one B-fragment for a 16-col
// group (t') and one k-chunk (kc=32 k's). lane=quad*16+l16 reads elements
// W[n0 + t'*16 + l16][kc*32 + quad*8 + e] at lane*8 -> one coalesced 1 KB
// global_load_dwordx4 per fragment.
__global__ void cvt_wf_kernel(const float* __restrict__ src, bf16* __restrict__ dst,
                              int Nc, int K) {
  int i = blockIdx.x * 256 + threadIdx.x;     // one thread per 8-elem group
  int total = Nc * (K >> 3);
  if (i >= total) return;
  int k8 = i % (K >> 3);
  int n  = i / (K >> 3);
  int kc = k8 >> 2, quad = k8 & 3;
  int nb = n >> 7, nn = n & 127, tp = nn >> 4, l = nn & 15;
  int KC = K >> 5;
  size_t di = (((size_t)nb * KC + kc) * 8 + tp) * 512 + quad * 128 + l * 8;
  const float* s = src + (size_t)n * K + k8 * 8;
  #pragma unroll
  for (int e = 0; e < 8; ++e) dst[di + e] = f2b(s[e]);
}

// ---------------- block-wide sum over 256 threads (4 waves) ----------------
__device__ __forceinline__ float block_sum(float v, float* red) {
  #pragma unroll
  for (int off = 32; off >= 1; off >>= 1) v += __shfl_xor(v, off, 64);
  int w = threadIdx.x >> 6;
  if ((threadIdx.x & 63) == 0) red[w] = v;
  __syncthreads();
  float r = red[0] + red[1] + red[2] + red[3];
  __syncthreads();
  return r;
}

// ---------------- Kernel 1: LA pooling + channel MLP + fusion --------------
__global__ void la_pool_kernel(const float* __restrict__ x,
                               const float* __restrict__ f1w, const float* __restrict__ f1bias,
                               const float* __restrict__ f2w, const float* __restrict__ f2bias,
                               const float* __restrict__ vw,  const float* __restrict__ vbias,
                               float* __restrict__ fusion7) {
  int blk = blockIdx.x;
  int b = blk / 49, p = blk % 49;
  int h7 = p / 7, w7 = p % 7;
  int tid = threadIdx.x;
  int head = tid >> 4;     // 0..15
  int j = tid & 15;        // 0..15

  float sum = 0.f, mx = -3.0e38f;
  #pragma unroll
  for (int a = 0; a < 2; ++a) {
    #pragma unroll
    for (int bb = 0; bb < 2; ++bb) {
      int tok = 1 + (2 * h7 + a) * 14 + (2 * w7 + bb);
      const float* row = x + ((size_t)b * N + tok) * C + head * 48;
      #pragma unroll
      for (int s = 0; s < 3; ++s) {
        float v = row[j + 16 * s];
        sum += v;
        mx = fmaxf(mx, v);
      }
    }
  }
  #pragma unroll
  for (int off = 8; off >= 1; off >>= 1) {
    sum += __shfl_xor(sum, off, 64);
    mx = fmaxf(mx, __shfl_xor(mx, off, 64));
  }
  __shared__ float s_mean[16], s_max[16];
  if (j == 0) { s_mean[head] = sum / 192.f; s_max[head] = mx; }
  __syncthreads();
  if (tid < 16) {
    float hm = f1bias[0], hx = hm;
    #pragma unroll
    for (int h = 0; h < 16; ++h) {
      float w = f1w[h];
      hm += s_mean[h] * w;
      hx += s_max[h] * w;
    }
    hm = fmaxf(hm, 0.f);
    hx = fmaxf(hx, 0.f);
    float w2 = f2w[tid], b2v = f2bias[tid];
    float m   = hm * w2 + b2v;
    float mxv = hx * w2 + b2v;
    float fus = vw[0] * m + vw[1] * mxv + vbias[0];
    fusion7[((size_t)b * 16 + tid) * 49 + p] = fus;
  }
}

// ---------------- Kernel 2: gate (bilinear resize + sigmoid) + LN1 ---------
__global__ void gate_ln1_kernel(const float* __restrict__ x, const float* __restrict__ fusion7,
                                const float* __restrict__ g, const float* __restrict__ beta,
                                bf16* __restrict__ ln1) {
  int blk = blockIdx.x;
  int b = blk / N, n = blk % N;
  int tid = threadIdx.x;
  __shared__ float gates[16];
  __shared__ float red[4];

  if (tid < 16) {
    if (n > 0) {
      int hh = (n - 1) / 14, ww = (n - 1) % 14;
      float ch = fminf(fmaxf(hh * 0.5f - 0.25f, 0.f), 6.f);
      float cw = fminf(fmaxf(ww * 0.5f - 0.25f, 0.f), 6.f);
      int h0 = (int)floorf(ch); int h1 = min(h0 + 1, 6); float fh = ch - (float)h0;
      int w0 = (int)floorf(cw); int w1 = min(w0 + 1, 6); float fw = cw - (float)w0;
      const float* fp = fusion7 + ((size_t)b * 16 + tid) * 49;
      float v00 = fp[h0 * 7 + w0], v01 = fp[h0 * 7 + w1];
      float v10 = fp[h1 * 7 + w0], v11 = fp[h1 * 7 + w1];
      float v = (1.f - fh) * ((1.f - fw) * v00 + fw * v01)
              + fh        * ((1.f - fw) * v10 + fw * v11);
      gates[tid] = 1.f / (1.f + expf(-v));
    } else {
      gates[tid] = 0.f;   // cls token: multiplier (1+0) == identity
    }
  }
  __syncthreads();

  const float* xr = x + ((size_t)b * N + n) * C;
  float v[3];
  #pragma unroll
  for (int s = 0; s < 3; ++s) {
    int c = tid + 256 * s;
    v[s] = xr[c] * (1.f + gates[c / 48]);
  }
  float mu = block_sum(v[0] + v[1] + v[2], red) * (1.f / 768.f);
  float d0 = v[0] - mu, d1 = v[1] - mu, d2 = v[2] - mu;
  float var = block_sum(d0 * d0 + d1 * d1 + d2 * d2, red) * (1.f / 768.f);
  float rs = rsqrtf(var + EPS);
  bf16* orow = ln1 + ((size_t)b * N + n) * C;
  #pragma unroll
  for (int s = 0; s < 3; ++s) {
    int c = tid + 256 * s;
    orow[c] = f2b((v[s] - mu) * rs * g[c] + beta[c]);
  }
}

// ---------------- Kernel 3: LN over bf16 input -> bf16 ---------------------
__global__ void ln_bf16_kernel(const bf16* __restrict__ xin,
                               const float* __restrict__ g, const float* __restrict__ beta,
                               bf16* __restrict__ out) {
  int row = blockIdx.x;
  int tid = threadIdx.x;
  __shared__ float red[4];
  const bf16* xr = xin + (size_t)row * C;
  float v[3];
  #pragma unroll
  for (int s = 0; s < 3; ++s) v[s] = b2f(xr[tid + 256 * s]);
  float mu = block_sum(v[0] + v[1] + v[2], red) * (1.f / 768.f);
  float d0 = v[0] - mu, d1 = v[1] - mu, d2 = v[2] - mu;
  float var = block_sum(d0 * d0 + d1 * d1 + d2 * d2, red) * (1.f / 768.f);
  float rs = rsqrtf(var + EPS);
  bf16* orow = out + (size_t)row * C;
  #pragma unroll
  for (int s = 0; s < 3; ++s) {
    int c = tid + 256 * s;
    orow[c] = f2b((v[s] - mu) * rs * g[c] + beta[c]);
  }
}

// ---------------- Kernel 4: 128x128 tile, A via LDS dbuf, B from global ----
// C[M,Nc] = A[M,K]*W[Nc,K]^T + bias. W pre-shuffled to fragment layout (Wf).
// EPI: 0=bias, 1=bias+exact gelu. XCD-swizzled 1-D grid (see r7 comment).
// LDS traffic halved vs r7: only A staged (8 KB/iter) + 4 ds_read_b128/wave.
template <int EPI, int K>
__global__ void gemm128(const bf16* __restrict__ A, const bf16* __restrict__ Wf,
                        const float* __restrict__ bias,
                        const float* __restrict__ resF, const bf16* __restrict__ resB,
                        bf16* __restrict__ outB, float* __restrict__ outF, int Nc) {
  constexpr int KC = K >> 5;
  int nx = Nc >> 7;
  int g = blockIdx.x;
  int c = g & 7, t = g >> 3;
  int x = t % nx;
  int y = c + 8 * (t / nx);
  if (y >= MT) return;                 // padded tail
  int m0 = y * 128;
  int n0 = x * 128;

  __shared__ __align__(16) bf16 sA[2][128 * 32];
  int tid = threadIdx.x;
  int wave = tid >> 6, lane = tid & 63, quad = lane >> 4, l16 = lane & 15;

  // A staging: one issue = 16 rows x 64B. wave w covers rows w*32..w*32+31.
  int ln16 = lane >> 2, seg = lane & 3;
  int sw = seg ^ ((ln16 >> 1) & 3);                 // swizzled chunk in row
  const bf16* gA = A + (size_t)(m0 + wave * 32 + ln16) * K + sw * 8;

  int wm = (wave & 1) * 64, wn = (wave >> 1) * 64;  // wave quadrant
  int csw = (l16 >> 1) & 3;                         // fragment-read swizzle
  // B fragments direct from global (Wf layout): per (kc, t') slab of 1 KB.
  const bf16* wfb = Wf + ((size_t)(n0 >> 7) * KC) * 4096 + (wn >> 4) * 512 + lane * 8;

  floatx4 acc[4][4] = {};

  // preload B frags for kc=0
  short8 bw[4];
  #pragma unroll
  for (int t2 = 0; t2 < 4; ++t2)
    bw[t2] = *reinterpret_cast<const short8*>(wfb + t2 * 512);

  // prologue: stage A k-chunk 0 into buffer 0
  #pragma unroll
  for (int i = 0; i < 2; ++i)
    load_lds16(gA + (size_t)(i * 16) * K, &sA[0][(wave * 32 + i * 16) * 32]);

  int p = 0;
  for (int kc = 0; kc < KC; ++kc, p ^= 1) {
    __syncthreads();                    // publishes A buffer p
    if (kc + 1 < KC) {                  // prefetch A chunk kc+1
      #pragma unroll
      for (int i = 0; i < 2; ++i)
        load_lds16(gA + (size_t)(i * 16) * K + (kc + 1) * 32,
                   &sA[p ^ 1][(wave * 32 + i * 16) * 32]);
    }
    short8 bwn[4] = {bw[0], bw[1], bw[2], bw[3]};
    if (kc + 1 < KC) {                  // prefetch B frags kc+1 (registers)
      #pragma unroll
      for (int t2 = 0; t2 < 4; ++t2)
        bwn[t2] = *reinterpret_cast<const short8*>(wfb + (size_t)(kc + 1) * 4096 + t2 * 512);
    }
    short8 af[4];
    #pragma unroll
    for (int s = 0; s < 4; ++s) {
      int row = wm + s * 16 + l16;
      af[s] = *reinterpret_cast<const short8*>(&sA[p][row * 32 + ((quad ^ csw) * 8)]);
    }
    #pragma unroll
    for (int s = 0; s < 4; ++s)
      #pragma unroll
      for (int t2 = 0; t2 < 4; ++t2)
        acc[s][t2] = __builtin_amdgcn_mfma_f32_16x16x32_bf16(af[s], bw[t2], acc[s][t2], 0, 0, 0);
    #pragma unroll
    for (int t2 = 0; t2 < 4; ++t2) bw[t2] = bwn[t2];
  }

  #pragma unroll
  for (int t2 = 0; t2 < 4; ++t2) {
    int col = n0 + wn + t2 * 16 + l16;
    float bv = bias[col];
    #pragma unroll
    for (int s = 0; s < 4; ++s) {
      int rowb = m0 + wm + s * 16 + quad * 4;
      #pragma unroll
      for (int r = 0; r < 4; ++r) {
        int row = rowb + r;
        if (row < M) {
          float v = acc[s][t2][r] + bv;
          if (EPI == 1) v = 0.5f * v * (1.f + erff(v * 0.7071067811865475f));
          size_t idx = (size_t)row * Nc + col;
          if (resF) v += resF[idx];
          if (resB) v += b2f(resB[idx]);
          if (outF) outF[idx] = v;
          if (outB) outB[idx] = f2b(v);
        }
      }
    }
  }
}

// ---------------- Kernel 5: MFMA attention, one block per (b, head) --------
__global__ void attn_mfma_kernel(const bf16* __restrict__ qkv, bf16* __restrict__ attn_o) {
  int bh = blockIdx.x;
  int h = bh % NH, b = bh / NH;
  int tid = threadIdx.x;
  int wave = tid >> 6, lane = tid & 63, quad = lane >> 4, l16 = lane & 15;

  __shared__ __align__(16) bf16 sVt[64][232];     // V^T: [d][m], m>=197 zero
  __shared__ __align__(16) bf16 sP[4][16][232];   // per-wave P: [q][m]

  const bf16* base = qkv + (size_t)b * N * 2304 + h * 64;

  {
    int d = tid & 63;
    for (int m = tid >> 6; m < 224; m += 4) {
      sVt[d][m] = (m < N) ? base[(size_t)m * 2304 + 1536 + d] : f2b(0.f);
    }
  }
  __syncthreads();

  const float scale = 0.125f;   // 64^-0.5

  for (int qt = wave; qt < 13; qt += 4) {
    int qr = min(qt * 16 + l16, N - 1);
    const bf16* qp = base + (size_t)qr * 2304;
    short8 aq0 = *reinterpret_cast<const short8*>(qp + quad * 8);
    short8 aq1 = *reinterpret_cast<const short8*>(qp + 32 + quad * 8);

    floatx4 s[13];
    #pragma unroll
    for (int kt = 0; kt < 13; ++kt) {
      int kr = min(kt * 16 + l16, N - 1);
      const bf16* kp = base + (size_t)kr * 2304 + 768;
      short8 bk0 = *reinterpret_cast<const short8*>(kp + quad * 8);
      short8 bk1 = *reinterpret_cast<const short8*>(kp + 32 + quad * 8);
      floatx4 acc = floatx4{0.f, 0.f, 0.f, 0.f};
      acc = __builtin_amdgcn_mfma_f32_16x16x32_bf16(aq0, bk0, acc, 0, 0, 0);
      acc = __builtin_amdgcn_mfma_f32_16x16x32_bf16(aq1, bk1, acc, 0, 0, 0);
      s[kt] = acc;
    }

    bool cv[13];
    #pragma unroll
    for (int kt = 0; kt < 13; ++kt) cv[kt] = (kt * 16 + l16) < N;

    float mx[4] = {-3.0e38f, -3.0e38f, -3.0e38f, -3.0e38f};
    #pragma unroll
    for (int kt = 0; kt < 13; ++kt) {
      #pragma unroll
      for (int r = 0; r < 4; ++r) {
        float sv = s[kt][r] * scale;
        s[kt][r] = sv;
        if (cv[kt]) mx[r] = fmaxf(mx[r], sv);
      }
    }
    #pragma unroll
    for (int off = 8; off >= 1; off >>= 1) {
      #pragma unroll
      for (int r = 0; r < 4; ++r) mx[r] = fmaxf(mx[r], __shfl_xor(mx[r], off, 64));
    }
    float sum[4] = {0.f, 0.f, 0.f, 0.f};
    #pragma unroll
    for (int kt = 0; kt < 13; ++kt) {
      #pragma unroll
      for (int r = 0; r < 4; ++r) {
        float e = cv[kt] ? expf(s[kt][r] - mx[r]) : 0.f;
        s[kt][r] = e;
        sum[r] += e;
      }
    }
    #pragma unroll
    for (int off = 8; off >= 1; off >>= 1) {
      #pragma unroll
      for (int r = 0; r < 4; ++r) sum[r] += __shfl_xor(sum[r], off, 64);
    }
    float inv[4];
    #pragma unroll
    for (int r = 0; r < 4; ++r) inv[r] = 1.f / sum[r];

    #pragma unroll
    for (int kt = 0; kt < 13; ++kt) {
      #pragma unroll
      for (int r = 0; r < 4; ++r)
        sP[wave][quad * 4 + r][kt * 16 + l16] = f2b(s[kt][r]);
    }
    #pragma unroll
    for (int r = 0; r < 4; ++r)
      sP[wave][quad * 4 + r][208 + l16] = f2b(0.f);

    floatx4 o[4] = {floatx4{0,0,0,0}, floatx4{0,0,0,0}, floatx4{0,0,0,0}, floatx4{0,0,0,0}};
    #pragma unroll
    for (int c = 0; c < 7; ++c) {
      short8 ap = *reinterpret_cast<const short8*>(&sP[wave][l16][c * 32 + quad * 8]);
      #pragma unroll
      for (int t = 0; t < 4; ++t) {
        short8 bv = *reinterpret_cast<const short8*>(&sVt[t * 16 + l16][c * 32 + quad * 8]);
        o[t] = __builtin_amdgcn_mfma_f32_16x16x32_bf16(ap, bv, o[t], 0, 0, 0);
      }
    }

    #pragma unroll
    for (int t = 0; t < 4; ++t) {
      #pragma unroll
      for (int r = 0; r < 4; ++r) {
        int qrow = qt * 16 + quad * 4 + r;
        if (qrow < N)
          attn_o[((size_t)b * N + qrow) * C + h * 64 + t * 16 + l16] = f2b(o[t][r] * inv[r]);
      }
    }
  }
}

// ---------------- host-side orchestration ----------------------------------
extern "C" void kernel_launch(void* const* d_in, const int* in_sizes, int n_in,
                              void* d_out, int out_size, void* d_ws, size_t ws_size,
                              hipStream_t stream) {
  (void)in_sizes; (void)n_in; (void)out_size; (void)ws_size;
  const float* x       = (const float*)d_in[0];
  const float* norm1_g = (const float*)d_in[1];
  const float* norm1_b = (const float*)d_in[2];
  const float* qkv_w   = (const float*)d_in[3];
  const float* qkv_b   = (const float*)d_in[4];
  const float* proj_w  = (const float*)d_in[5];
  const float* proj_b  = (const float*)d_in[6];
  const float* norm2_g = (const float*)d_in[7];
  const float* norm2_b = (const float*)d_in[8];
  const float* fc1_w   = (const float*)d_in[9];
  const float* fc1_b   = (const float*)d_in[10];
  const float* fc2_w   = (const float*)d_in[11];
  const float* fc2_b   = (const float*)d_in[12];
  const float* f1_w    = (const float*)d_in[13];
  const float* f1_b    = (const float*)d_in[14];
  const float* f2_w    = (const float*)d_in[15];
  const float* f2_b    = (const float*)d_in[16];
  const float* v_w     = (const float*)d_in[17];
  const float* v_b     = (const float*)d_in[18];
  float* out = (float*)d_out;

  char* ws = (char*)d_ws;
  // ws layout (~131.2 MB). Activation buffers padded to MPAD=12672 rows.
  float* fusion7 = (float*)(ws + 0);                //    200,704
  bf16*  qkv_wf  = (bf16*)(ws + 262144);            //  3,538,944
  bf16*  proj_wf = (bf16*)(ws + 3801088);           //  1,179,648
  bf16*  fc1_wf  = (bf16*)(ws + 4980736);           //  4,718,592
  bf16*  fc2_wf  = (bf16*)(ws + 9699328);           //  4,718,592
  bf16*  ln1     = (bf16*)(ws + 14417920);          // 19,464,192 (MPAD x 768; reused: attn_o, ln2)
  bf16*  attn_o  = ln1;
  bf16*  ln2     = ln1;
  bf16*  qkvb    = (bf16*)(ws + 33882112);          // 77,856,768 (qkv MPADx2304; reused hbuf MPADx3072)
  bf16*  hbuf    = qkvb;
  bf16*  x2b     = (bf16*)(ws + 111738880);         // 19,464,192 (MPAD x 768 bf16) -> end 131,203,072

  cvt_wf_kernel<<<(2304 * 96 + 255) / 256, 256, 0, stream>>>(qkv_w, qkv_wf, 2304, 768);
  cvt_wf_kernel<<<(768 * 96 + 255) / 256, 256, 0, stream>>>(proj_w, proj_wf, 768, 768);
  cvt_wf_kernel<<<(3072 * 96 + 255) / 256, 256, 0, stream>>>(fc1_w, fc1_wf, 3072, 768);
  cvt_wf_kernel<<<(768 * 384 + 255) / 256, 256, 0, stream>>>(fc2_w, fc2_wf, 768, 3072);

  la_pool_kernel<<<B * 49, 256, 0, stream>>>(x, f1_w, f1_b, f2_w, f2_b, v_w, v_b, fusion7);
  gate_ln1_kernel<<<B * N, 256, 0, stream>>>(x, fusion7, norm1_g, norm1_b, ln1);
  // qkv: (M x 768) x (2304 x 768)^T -> bf16
  gemm128<0, 768><<<(2304 / 128) * MTP, 256, 0, stream>>>(
      ln1, qkv_wf, qkv_b, nullptr, nullptr, qkvb, nullptr, 2304);
  attn_mfma_kernel<<<B * NH, 256, 0, stream>>>(qkvb, attn_o);
  // proj + residual(x f32) -> x2b (bf16)
  gemm128<0, 768><<<(768 / 128) * MTP, 256, 0, stream>>>(
      attn_o, proj_wf, proj_b, x, nullptr, x2b, nullptr, 768);
  ln_bf16_kernel<<<M, 256, 0, stream>>>(x2b, norm2_g, norm2_b, ln2);
  // fc1 + gelu -> hbuf (bf16)
  gemm128<1, 768><<<(HID / 128) * MTP, 256, 0, stream>>>(
      ln2, fc1_wf, fc1_b, nullptr, nullptr, hbuf, nullptr, HID);
  // fc2 + residual(x2b bf16) -> out (f32)
  gemm128<0, 3072><<<(768 / 128) * MTP, 256, 0, stream>>>(
      hbuf, fc2_wf, fc2_b, nullptr, x2b, nullptr, out, 768);
}